// Round 1
// baseline (1439.803 us; speedup 1.0000x reference)
//
#include <hip/hip_runtime.h>
#include <math.h>

// Problem constants (B=2, Hs=Ws=48, D=768, heads=6, P=4)
#define BB 2
#define NN 12096     // 21 * (48*48/4)
#define LL 2304      // 48*48
#define DD 768
#define NH 6
#define PP 4
#define DH 128
#define HID 192
#define HS 48
#define WS 48

// ---------------- LayerNorm: one block per row of 768 ----------------
__global__ __launch_bounds__(256) void ln_kernel(const float* __restrict__ x,
                                                 const float* __restrict__ g,
                                                 const float* __restrict__ bta,
                                                 float* __restrict__ y) {
  size_t row = blockIdx.x;
  const float* xr = x + row * DD;
  int t = threadIdx.x;
  float v0 = xr[t], v1 = xr[t + 256], v2 = xr[t + 512];
  float s = v0 + v1 + v2;
  float s2 = v0 * v0 + v1 * v1 + v2 * v2;
#pragma unroll
  for (int off = 32; off; off >>= 1) {
    s += __shfl_down(s, off, 64);
    s2 += __shfl_down(s2, off, 64);
  }
  __shared__ float red[8];
  __shared__ float mv[2];
  int wave = t >> 6, lane = t & 63;
  if (lane == 0) { red[wave] = s; red[4 + wave] = s2; }
  __syncthreads();
  if (t == 0) {
    float ts = red[0] + red[1] + red[2] + red[3];
    float ts2 = red[4] + red[5] + red[6] + red[7];
    float m = ts * (1.f / DD);
    float var = ts2 * (1.f / DD) - m * m;
    mv[0] = m;
    mv[1] = rsqrtf(var + 1e-6f);
  }
  __syncthreads();
  float m = mv[0], rs = mv[1];
  float* yr = y + row * DD;
  yr[t]       = (v0 - m) * rs * g[t]       + bta[t];
  yr[t + 256] = (v1 - m) * rs * g[t + 256] + bta[t + 256];
  yr[t + 512] = (v2 - m) * rs * g[t + 512] + bta[t + 512];
}

// ---------------- Generic fp32 tiled GEMM: C = A(MxK) @ B(KxN) + bias (+res) ----------------
template <bool HAS_RES>
__global__ __launch_bounds__(256) void gemm_kernel(const float* __restrict__ A,
                                                   const float* __restrict__ B,
                                                   const float* __restrict__ bias,
                                                   const float* __restrict__ res,
                                                   float* __restrict__ C,
                                                   int M, int N, int K) {
  __shared__ float As[16][68];  // [k][m], row stride 68*4=272B (16B multiple)
  __shared__ float Bs[16][68];  // [k][n]
  int tid = threadIdx.x;
  int m0 = blockIdx.y * 64, n0 = blockIdx.x * 64;
  int ty = tid >> 4, tx = tid & 15;
  float acc[4][4] = {};
  int arow = tid >> 2, akq = (tid & 3) * 4;   // A: 64 rows x 16 k
  int brow = tid >> 4, bnq = (tid & 15) * 4;  // B: 16 k x 64 n
  for (int k0 = 0; k0 < K; k0 += 16) {
    float4 av = *(const float4*)&A[(size_t)(m0 + arow) * K + k0 + akq];
    float4 bv4 = *(const float4*)&B[(size_t)(k0 + brow) * N + n0 + bnq];
    As[akq + 0][arow] = av.x;
    As[akq + 1][arow] = av.y;
    As[akq + 2][arow] = av.z;
    As[akq + 3][arow] = av.w;
    *(float4*)&Bs[brow][bnq] = bv4;
    __syncthreads();
#pragma unroll
    for (int kk = 0; kk < 16; ++kk) {
      float a[4], b[4];
#pragma unroll
      for (int i = 0; i < 4; ++i) a[i] = As[kk][ty * 4 + i];
#pragma unroll
      for (int j = 0; j < 4; ++j) b[j] = Bs[kk][tx * 4 + j];
#pragma unroll
      for (int i = 0; i < 4; ++i)
#pragma unroll
        for (int j = 0; j < 4; ++j) acc[i][j] += a[i] * b[j];
    }
    __syncthreads();
  }
#pragma unroll
  for (int i = 0; i < 4; ++i) {
    int m = m0 + ty * 4 + i;
#pragma unroll
    for (int j = 0; j < 4; ++j) {
      int n = n0 + tx * 4 + j;
      float v = acc[i][j] + bias[n];
      if (HAS_RES) v += res[(size_t)m * N + n];
      C[(size_t)m * N + n] = v;
    }
  }
}

// ---------------- offsets + attention logits + softmax -> meta (x,y,aw)*24 per row ----------------
__global__ __launch_bounds__(128) void offattn_kernel(const float* __restrict__ qn,
                                                      const float* __restrict__ Woff,
                                                      const float* __restrict__ boff,
                                                      const float* __restrict__ Wattn,
                                                      const float* __restrict__ battn,
                                                      const float* __restrict__ refp,
                                                      float* __restrict__ meta) {
  size_t row = blockIdx.x;
  __shared__ float q[DD];
  __shared__ float offs[48];
  __shared__ float logit[24];
  int t = threadIdx.x;
#pragma unroll
  for (int i = 0; i < 6; ++i) q[t + i * 128] = qn[row * DD + t + i * 128];
  __syncthreads();
  if (t < 48) {
    float acc = boff[t];
    for (int k = 0; k < DD; ++k) acc += q[k] * Woff[k * 48 + t];
    offs[t] = acc;
  } else if (t < 72) {
    int j = t - 48;
    float acc = battn[j];
    for (int k = 0; k < DD; ++k) acc += q[k] * Wattn[k * 24 + j];
    logit[j] = acc;
  }
  __syncthreads();
  if (t < 24) {
    int hh = t >> 2;
    float l0 = logit[hh * 4], l1 = logit[hh * 4 + 1], l2 = logit[hh * 4 + 2], l3 = logit[hh * 4 + 3];
    float mx = fmaxf(fmaxf(l0, l1), fmaxf(l2, l3));
    float e = expf(logit[t] - mx);
    float sum = expf(l0 - mx) + expf(l1 - mx) + expf(l2 - mx) + expf(l3 - mx);
    float aw = e / sum;
    // x = ref.x*W + off.x - 0.5 (norm = W = 48 cancels)
    float rx = refp[row * 2 + 0] * (float)WS - 0.5f;
    float ry = refp[row * 2 + 1] * (float)HS - 0.5f;
    int p = t & 3;
    meta[row * 72 + t * 3 + 0] = rx + offs[hh * 8 + p * 2 + 0];
    meta[row * 72 + t * 3 + 1] = ry + offs[hh * 8 + p * 2 + 1];
    meta[row * 72 + t * 3 + 2] = aw;
  }
}

// ---------------- bilinear sampling + attention-weighted sum -> s (B,N,768) ----------------
__global__ __launch_bounds__(256) void sample_kernel(const float* __restrict__ value,
                                                     const float* __restrict__ meta,
                                                     float* __restrict__ s) {
  size_t row = blockIdx.x;  // b*N + n
  int b = (int)(row / NN);
  __shared__ float mt[72];
  __shared__ int cidx[96];
  __shared__ float cw[96];
  int t = threadIdx.x;
  if (t < 72) mt[t] = meta[row * 72 + t];
  __syncthreads();
  if (t < 24) {
    float x = mt[t * 3], y = mt[t * 3 + 1], aw = mt[t * 3 + 2];
    float xf = floorf(x), yf = floorf(y);
    int x0 = (int)xf, y0 = (int)yf;
    float wx = x - xf, wy = y - yf;
#pragma unroll
    for (int c = 0; c < 4; ++c) {
      int xi = x0 + (c & 1), yi = y0 + (c >> 1);
      float w = ((c & 1) ? wx : 1.f - wx) * ((c >> 1) ? wy : 1.f - wy);
      bool valid = (xi >= 0) && (xi < WS) && (yi >= 0) && (yi < HS);
      int xc = min(max(xi, 0), WS - 1), yc = min(max(yi, 0), HS - 1);
      cidx[t * 4 + c] = yc * WS + xc;
      cw[t * 4 + c] = valid ? w * aw : 0.f;
    }
  }
  __syncthreads();
  const float* vb = value + (size_t)b * LL * DD;
  for (int c = t; c < DD; c += 256) {
    int h = c >> 7;
    float acc = 0.f;
#pragma unroll
    for (int pp = 0; pp < 4; ++pp) {
      int base = (h * 4 + pp) * 4;
#pragma unroll
      for (int cc = 0; cc < 4; ++cc) {
        float w = cw[base + cc];
        acc += w * vb[(size_t)cidx[base + cc] * DD + c];
      }
    }
    s[row * DD + c] = acc;
  }
}

// ---------------- depthwise 3x3 (3 scales) + exact GELU ----------------
__global__ __launch_bounds__(256) void dwconv_gelu_kernel(const float* __restrict__ h,
                                                          const float* __restrict__ w,
                                                          const float* __restrict__ bias,
                                                          float* __restrict__ out) {
  size_t idx = (size_t)blockIdx.x * 256 + threadIdx.x;
  if (idx >= (size_t)BB * NN * HID) return;
  int c = (int)(idx % HID);
  int rem = (int)(idx / HID);
  int nidx = rem % NN;
  int b = rem / NN;
  int hh, ww, base;
  if (nidx < 9216)       { hh = 96; ww = 96; base = 0; }
  else if (nidx < 11520) { hh = 48; ww = 48; base = 9216; }
  else                   { hh = 24; ww = 24; base = 11520; }
  int p = nidx - base;
  int y = p / ww, x = p % ww;
  const float* hb = h + ((size_t)b * NN + base) * HID;
  float acc = bias[c];
#pragma unroll
  for (int dy = -1; dy <= 1; ++dy) {
    int yy = y + dy;
    if (yy < 0 || yy >= hh) continue;
#pragma unroll
    for (int dx = -1; dx <= 1; ++dx) {
      int xx = x + dx;
      if (xx < 0 || xx >= ww) continue;
      acc += hb[((size_t)(yy * ww + xx)) * HID + c] * w[c * 9 + (dy + 1) * 3 + (dx + 1)];
    }
  }
  float g = 0.5f * acc * (1.f + erff(acc * 0.70710678118654752f));
  out[idx] = g;
}

extern "C" void kernel_launch(void* const* d_in, const int* in_sizes, int n_in,
                              void* d_out, int out_size, void* d_ws, size_t ws_size,
                              hipStream_t stream) {
  const float* query = (const float*)d_in[0];
  const float* refp  = (const float*)d_in[1];
  const float* feat  = (const float*)d_in[2];
  // d_in[3] spatial_shapes, d_in[4] level_start_index, d_in[5] H, d_in[6] W: constants hardcoded
  const float* qn_g  = (const float*)d_in[7];
  const float* qn_b  = (const float*)d_in[8];
  const float* fn_g  = (const float*)d_in[9];
  const float* fn_b  = (const float*)d_in[10];
  const float* Wv    = (const float*)d_in[11];
  const float* bv    = (const float*)d_in[12];
  const float* Woff  = (const float*)d_in[13];
  const float* boff  = (const float*)d_in[14];
  const float* Wattn = (const float*)d_in[15];
  const float* battn = (const float*)d_in[16];
  const float* Wo    = (const float*)d_in[17];
  const float* bo    = (const float*)d_in[18];
  const float* ffn_g = (const float*)d_in[19];
  const float* ffn_b = (const float*)d_in[20];
  const float* W1    = (const float*)d_in[21];
  const float* b1    = (const float*)d_in[22];
  const float* dw_w  = (const float*)d_in[23];
  const float* dw_b  = (const float*)d_in[24];
  const float* W2    = (const float*)d_in[25];
  const float* b2    = (const float*)d_in[26];
  float* out = (float*)d_out;

  float* ws = (float*)d_ws;
  float* buf_qn   = ws;                          // B*N*D (also reused for s, then ln2)
  float* buf_fn   = buf_qn + (size_t)BB * NN * DD;    // B*L*D
  float* buf_val  = buf_fn + (size_t)BB * LL * DD;    // B*L*D
  float* buf_meta = buf_val + (size_t)BB * LL * DD;   // B*N*72
  float* buf_h    = buf_meta + (size_t)BB * NN * 72;  // B*N*HID
  float* buf_h2   = buf_h + (size_t)BB * NN * HID;    // B*N*HID

  const int Mq = BB * NN;  // 24192
  const int Mf = BB * LL;  // 4608

  // 1-2: LayerNorms
  ln_kernel<<<Mq, 256, 0, stream>>>(query, qn_g, qn_b, buf_qn);
  ln_kernel<<<Mf, 256, 0, stream>>>(feat, fn_g, fn_b, buf_fn);
  // 3: value = fn @ Wv + bv
  gemm_kernel<false><<<dim3(DD / 64, Mf / 64), 256, 0, stream>>>(buf_fn, Wv, bv, nullptr, buf_val, Mf, DD, DD);
  // 4: offsets + attn weights + softmax -> meta
  offattn_kernel<<<Mq, 128, 0, stream>>>(buf_qn, Woff, boff, Wattn, battn, refp, buf_meta);
  // 5: bilinear sampling -> s (overwrites buf_qn; qn no longer needed)
  sample_kernel<<<Mq, 256, 0, stream>>>(buf_val, buf_meta, buf_qn);
  // 6: q2 = query + s @ Wo + bo -> d_out
  gemm_kernel<true><<<dim3(DD / 64, Mq / 64), 256, 0, stream>>>(buf_qn, Wo, bo, query, out, Mq, DD, DD);
  // 7: ln2 = LN(q2) -> buf_qn
  ln_kernel<<<Mq, 256, 0, stream>>>(out, ffn_g, ffn_b, buf_qn);
  // 8: h = ln2 @ W1 + b1
  gemm_kernel<false><<<dim3(HID / 64, Mq / 64), 256, 0, stream>>>(buf_qn, W1, b1, nullptr, buf_h, Mq, HID, DD);
  // 9: depthwise conv (3 scales) + GELU
  {
    size_t total = (size_t)BB * NN * HID;
    int blocks = (int)((total + 255) / 256);
    dwconv_gelu_kernel<<<blocks, 256, 0, stream>>>(buf_h, dw_w, dw_b, buf_h2);
  }
  // 10: out = q2 + h2 @ W2 + b2 (in-place residual)
  gemm_kernel<true><<<dim3(DD / 64, Mq / 64), 256, 0, stream>>>(buf_h2, W2, b2, out, out, Mq, DD, HID);
}

// Round 2
// 472.691 us; speedup vs baseline: 3.0460x; 3.0460x over previous
//
#include <hip/hip_runtime.h>
#include <math.h>

// Problem constants (B=2, Hs=Ws=48, D=768, heads=6, P=4)
#define BB 2
#define NN 12096     // 21 * (48*48/4)
#define LL 2304      // 48*48
#define DD 768
#define HID 192
#define HS 48
#define WS 48

typedef unsigned short u16;
typedef unsigned int u32;
typedef __attribute__((ext_vector_type(8))) __bf16 bf16x8;
typedef __attribute__((ext_vector_type(4))) float f32x4;

__device__ __forceinline__ u16 f2bf(float f) {
  u32 x = __builtin_bit_cast(u32, f);
  u32 r = (x + 0x7fffu + ((x >> 16) & 1u)) >> 16;  // RNE
  return (u16)r;
}
__device__ __forceinline__ float bf2f(u16 u) {
  u32 x = ((u32)u) << 16;
  return __builtin_bit_cast(float, x);
}

// ---------------- LayerNorm: one block per row of 768, bf16 output ----------------
__global__ __launch_bounds__(256) void ln_kernel(const float* __restrict__ x,
                                                 const float* __restrict__ g,
                                                 const float* __restrict__ bta,
                                                 u16* __restrict__ y) {
  size_t row = blockIdx.x;
  const float* xr = x + row * DD;
  int t = threadIdx.x;
  float v0 = xr[t], v1 = xr[t + 256], v2 = xr[t + 512];
  float s = v0 + v1 + v2;
  float s2 = v0 * v0 + v1 * v1 + v2 * v2;
#pragma unroll
  for (int off = 32; off; off >>= 1) {
    s += __shfl_down(s, off, 64);
    s2 += __shfl_down(s2, off, 64);
  }
  __shared__ float red[8];
  __shared__ float mv[2];
  int wave = t >> 6, lane = t & 63;
  if (lane == 0) { red[wave] = s; red[4 + wave] = s2; }
  __syncthreads();
  if (t == 0) {
    float ts = red[0] + red[1] + red[2] + red[3];
    float ts2 = red[4] + red[5] + red[6] + red[7];
    float m = ts * (1.f / DD);
    float var = ts2 * (1.f / DD) - m * m;
    mv[0] = m;
    mv[1] = rsqrtf(var + 1e-6f);
  }
  __syncthreads();
  float m = mv[0], rs = mv[1];
  u16* yr = y + row * DD;
  yr[t]       = f2bf((v0 - m) * rs * g[t]       + bta[t]);
  yr[t + 256] = f2bf((v1 - m) * rs * g[t + 256] + bta[t + 256]);
  yr[t + 512] = f2bf((v2 - m) * rs * g[t + 512] + bta[t + 512]);
}

// ---------------- bf16 MFMA GEMM: C(MxN) = A(MxK)bf16 @ Bt(NxK)bf16 + bias (+res) ----------------
// 256 threads = 4 waves arranged WM x WN; per-wave tile (BM/WM) x (BN/WN) of 16x16 MFMA frags.
// LDS: XOR-swizzled [row][chunk^(row&7)] 16B chunks so global_load_lds (no padding allowed)
// coexists with conflict-free ds_read_b128.
template <int BM, int BN, int WM, int WN, bool HAS_RES, bool OUT_BF16>
__global__ __launch_bounds__(256, 2) void gemm_bf16(const u16* __restrict__ A,
                                                    const u16* __restrict__ Bt,
                                                    const float* __restrict__ bias,
                                                    const float* __restrict__ res,
                                                    void* __restrict__ Cv,
                                                    int M, int N, int K) {
  constexpr int PM = BM / WM, PN = BN / WN;
  constexpr int FM = PM / 16, FN = PN / 16;
  constexpr int ASEG = BM / 32;  // staging calls per wave for A (1024B each)
  constexpr int BSEG = BN / 32;
  __shared__ u16 As[BM * 64];
  __shared__ u16 Bs[BN * 64];
  int tid = threadIdx.x;
  int w = tid >> 6, lane = tid & 63;
  int rw = w / WN, cw = w % WN;
  int m0 = blockIdx.y * BM, n0 = blockIdx.x * BN;

  f32x4 acc[FM][FN];
#pragma unroll
  for (int i = 0; i < FM; ++i)
#pragma unroll
    for (int j = 0; j < FN; ++j) acc[i][j] = (f32x4){0.f, 0.f, 0.f, 0.f};

  int lr = lane >> 3;       // row within 8-row segment
  int lq = lane & 7;        // destination 16B chunk within row
  int qg = lq ^ lr;         // swizzled source chunk
  int l15 = lane & 15, quad = lane >> 4;

  for (int k0 = 0; k0 < K; k0 += 64) {
#pragma unroll
    for (int i = 0; i < ASEG; ++i) {
      int s = w * ASEG + i;
      int row = s * 8 + lr;
      const u16* gp = A + (size_t)(m0 + row) * K + k0 + qg * 8;
      __builtin_amdgcn_global_load_lds(
          (const __attribute__((address_space(1))) void*)gp,
          (__attribute__((address_space(3))) void*)&As[s * 512], 16, 0, 0);
    }
#pragma unroll
    for (int i = 0; i < BSEG; ++i) {
      int s = w * BSEG + i;
      int row = s * 8 + lr;
      const u16* gp = Bt + (size_t)(n0 + row) * K + k0 + qg * 8;
      __builtin_amdgcn_global_load_lds(
          (const __attribute__((address_space(1))) void*)gp,
          (__attribute__((address_space(3))) void*)&Bs[s * 512], 16, 0, 0);
    }
    __syncthreads();
#pragma unroll
    for (int s2 = 0; s2 < 2; ++s2) {
      bf16x8 af[FM], bf[FN];
#pragma unroll
      for (int mt = 0; mt < FM; ++mt) {
        int rm = rw * PM + mt * 16 + l15;
        int ch = (s2 * 4 + quad) ^ (rm & 7);
        af[mt] = *(const bf16x8*)&As[rm * 64 + ch * 8];
      }
#pragma unroll
      for (int nt = 0; nt < FN; ++nt) {
        int rn = cw * PN + nt * 16 + l15;
        int ch = (s2 * 4 + quad) ^ (rn & 7);
        bf[nt] = *(const bf16x8*)&Bs[rn * 64 + ch * 8];
      }
#pragma unroll
      for (int mt = 0; mt < FM; ++mt)
#pragma unroll
        for (int nt = 0; nt < FN; ++nt)
          acc[mt][nt] = __builtin_amdgcn_mfma_f32_16x16x32_bf16(af[mt], bf[nt], acc[mt][nt], 0, 0, 0);
    }
    __syncthreads();
  }

#pragma unroll
  for (int mt = 0; mt < FM; ++mt) {
    int m = m0 + rw * PM + mt * 16 + quad * 4;
#pragma unroll
    for (int nt = 0; nt < FN; ++nt) {
      int n = n0 + cw * PN + nt * 16 + l15;
      float bsv = bias[n];
#pragma unroll
      for (int r = 0; r < 4; ++r) {
        float v = acc[mt][nt][r] + bsv;
        if (HAS_RES) v += res[(size_t)(m + r) * N + n];
        if (OUT_BF16) ((u16*)Cv)[(size_t)(m + r) * N + n] = f2bf(v);
        else ((float*)Cv)[(size_t)(m + r) * N + n] = v;
      }
    }
  }
}

// ---------------- weight prep: out[n*K+k] = bf16(in[k*N+n]) ----------------
__global__ __launch_bounds__(256) void prep_wt(const float* __restrict__ in, u16* __restrict__ out,
                                               int K, int N) {
  int idx = blockIdx.x * 256 + threadIdx.x;
  if (idx >= K * N) return;
  int n = idx / K, k = idx - n * K;
  out[idx] = f2bf(in[(size_t)k * N + n]);
}

// ---------------- concat+pad Woff|Wattn -> Wcat_t (128 x 768), bias_cat (128) ----------------
__global__ __launch_bounds__(256) void wcat_kernel(const float* __restrict__ Woff,
                                                   const float* __restrict__ Wattn,
                                                   const float* __restrict__ boff,
                                                   const float* __restrict__ battn,
                                                   u16* __restrict__ Wcat_t,
                                                   float* __restrict__ bias_cat) {
  int idx = blockIdx.x * 256 + threadIdx.x;
  if (idx >= 128 * DD) return;
  int n = idx / DD, k = idx - n * DD;
  float v = 0.f;
  if (n < 48) v = Woff[(size_t)k * 48 + n];
  else if (n < 72) v = Wattn[(size_t)k * 24 + (n - 48)];
  Wcat_t[idx] = f2bf(v);
  if (idx < 128) {
    float b = 0.f;
    if (idx < 48) b = boff[idx];
    else if (idx < 72) b = battn[idx - 48];
    bias_cat[idx] = b;
  }
}

// ---------------- softmax + sampling coords -> meta (x,y,aw)*24 per row ----------------
__global__ __launch_bounds__(256) void meta_kernel(const float* __restrict__ off,
                                                   const float* __restrict__ refp,
                                                   float* __restrict__ meta) {
  int idx = blockIdx.x * 256 + threadIdx.x;
  if (idx >= BB * NN * 24) return;
  int row = idx / 24, t = idx - row * 24;
  int hh = t >> 2, p = t & 3;
  const float* o = off + (size_t)row * 128;
  float l0 = o[48 + hh * 4 + 0], l1 = o[48 + hh * 4 + 1];
  float l2 = o[48 + hh * 4 + 2], l3 = o[48 + hh * 4 + 3];
  float mx = fmaxf(fmaxf(l0, l1), fmaxf(l2, l3));
  float e0 = expf(l0 - mx), e1 = expf(l1 - mx), e2 = expf(l2 - mx), e3 = expf(l3 - mx);
  float sum = e0 + e1 + e2 + e3;
  float et = (p == 0) ? e0 : (p == 1) ? e1 : (p == 2) ? e2 : e3;
  float aw = et / sum;
  float rx = refp[(size_t)row * 2 + 0] * (float)WS - 0.5f;
  float ry = refp[(size_t)row * 2 + 1] * (float)HS - 0.5f;
  meta[(size_t)row * 72 + t * 3 + 0] = rx + o[hh * 8 + p * 2 + 0];
  meta[(size_t)row * 72 + t * 3 + 1] = ry + o[hh * 8 + p * 2 + 1];
  meta[(size_t)row * 72 + t * 3 + 2] = aw;
}

// ---------------- bilinear sampling + attention-weighted sum -> s (bf16) ----------------
__global__ __launch_bounds__(256) void sample_kernel(const u16* __restrict__ value,
                                                     const float* __restrict__ meta,
                                                     u16* __restrict__ s) {
  size_t row = blockIdx.x;  // b*N + n
  int b = (int)(row / NN);
  __shared__ float mt[72];
  __shared__ int cidx[96];
  __shared__ float cw[96];
  int t = threadIdx.x;
  if (t < 72) mt[t] = meta[row * 72 + t];
  __syncthreads();
  if (t < 24) {
    float x = mt[t * 3], y = mt[t * 3 + 1], aw = mt[t * 3 + 2];
    float xf = floorf(x), yf = floorf(y);
    int x0 = (int)xf, y0 = (int)yf;
    float wx = x - xf, wy = y - yf;
#pragma unroll
    for (int c = 0; c < 4; ++c) {
      int xi = x0 + (c & 1), yi = y0 + (c >> 1);
      float w = ((c & 1) ? wx : 1.f - wx) * ((c >> 1) ? wy : 1.f - wy);
      bool valid = (xi >= 0) && (xi < WS) && (yi >= 0) && (yi < HS);
      int xc = min(max(xi, 0), WS - 1), yc = min(max(yi, 0), HS - 1);
      cidx[t * 4 + c] = yc * WS + xc;
      cw[t * 4 + c] = valid ? w * aw : 0.f;
    }
  }
  __syncthreads();
  const u16* vb = value + (size_t)b * LL * DD;
  for (int c = t; c < DD; c += 256) {
    int h = c >> 7;
    float acc = 0.f;
#pragma unroll
    for (int pp = 0; pp < 4; ++pp) {
      int base = (h * 4 + pp) * 4;
#pragma unroll
      for (int cc = 0; cc < 4; ++cc) {
        float w = cw[base + cc];
        acc += w * bf2f(vb[(size_t)cidx[base + cc] * DD + c]);
      }
    }
    s[row * DD + c] = f2bf(acc);
  }
}

// ---------------- depthwise 3x3 (3 scales) + exact GELU, bf16 in/out ----------------
__global__ __launch_bounds__(256) void dwconv_gelu_kernel(const u16* __restrict__ h,
                                                          const float* __restrict__ w,
                                                          const float* __restrict__ bias,
                                                          u16* __restrict__ out) {
  size_t idx = (size_t)blockIdx.x * 256 + threadIdx.x;
  if (idx >= (size_t)BB * NN * HID) return;
  int c = (int)(idx % HID);
  int rem = (int)(idx / HID);
  int nidx = rem % NN;
  int b = rem / NN;
  int hh, ww, base;
  if (nidx < 9216)       { hh = 96; ww = 96; base = 0; }
  else if (nidx < 11520) { hh = 48; ww = 48; base = 9216; }
  else                   { hh = 24; ww = 24; base = 11520; }
  int p = nidx - base;
  int y = p / ww, x = p % ww;
  const u16* hb = h + ((size_t)b * NN + base) * HID;
  float acc = bias[c];
#pragma unroll
  for (int dy = -1; dy <= 1; ++dy) {
    int yy = y + dy;
    if (yy < 0 || yy >= hh) continue;
#pragma unroll
    for (int dx = -1; dx <= 1; ++dx) {
      int xx = x + dx;
      if (xx < 0 || xx >= ww) continue;
      acc += bf2f(hb[((size_t)(yy * ww + xx)) * HID + c]) * w[c * 9 + (dy + 1) * 3 + (dx + 1)];
    }
  }
  float g = 0.5f * acc * (1.f + erff(acc * 0.70710678118654752f));
  out[idx] = f2bf(g);
}

extern "C" void kernel_launch(void* const* d_in, const int* in_sizes, int n_in,
                              void* d_out, int out_size, void* d_ws, size_t ws_size,
                              hipStream_t stream) {
  const float* query = (const float*)d_in[0];
  const float* refp  = (const float*)d_in[1];
  const float* feat  = (const float*)d_in[2];
  const float* qn_g  = (const float*)d_in[7];
  const float* qn_b  = (const float*)d_in[8];
  const float* fn_g  = (const float*)d_in[9];
  const float* fn_b  = (const float*)d_in[10];
  const float* Wv    = (const float*)d_in[11];
  const float* bv    = (const float*)d_in[12];
  const float* Woff  = (const float*)d_in[13];
  const float* boff  = (const float*)d_in[14];
  const float* Wattn = (const float*)d_in[15];
  const float* battn = (const float*)d_in[16];
  const float* Wo    = (const float*)d_in[17];
  const float* bo    = (const float*)d_in[18];
  const float* ffn_g = (const float*)d_in[19];
  const float* ffn_b = (const float*)d_in[20];
  const float* W1    = (const float*)d_in[21];
  const float* b1    = (const float*)d_in[22];
  const float* dw_w  = (const float*)d_in[23];
  const float* dw_b  = (const float*)d_in[24];
  const float* W2    = (const float*)d_in[25];
  const float* b2    = (const float*)d_in[26];
  float* out = (float*)d_out;

  const int Mq = BB * NN;  // 24192
  const int Mf = BB * LL;  // 4608

  char* p = (char*)d_ws;
  auto alloc = [&](size_t bytes) { char* r = p; p += (bytes + 255) & ~(size_t)255; return r; };
  u16* qn_bf   = (u16*)alloc((size_t)Mq * DD * 2);   // also reused for ln2
  u16* fn_bf   = (u16*)alloc((size_t)Mf * DD * 2);
  u16* val_bf  = (u16*)alloc((size_t)Mf * DD * 2);
  float* off   = (float*)alloc((size_t)Mq * 128 * 4);
  float* meta  = (float*)alloc((size_t)Mq * 72 * 4);
  u16* s_bf    = (u16*)alloc((size_t)Mq * DD * 2);
  u16* h_bf    = (u16*)alloc((size_t)Mq * HID * 2);
  u16* h2_bf   = (u16*)alloc((size_t)Mq * HID * 2);
  u16* Wv_t    = (u16*)alloc((size_t)DD * DD * 2);
  u16* Wo_t    = (u16*)alloc((size_t)DD * DD * 2);
  u16* W1_t    = (u16*)alloc((size_t)HID * DD * 2);
  u16* W2_t    = (u16*)alloc((size_t)DD * HID * 2);
  u16* Wcat_t  = (u16*)alloc((size_t)128 * DD * 2);
  float* bias_cat = (float*)alloc(128 * 4);

  // weight prep
  prep_wt<<<(DD * DD + 255) / 256, 256, 0, stream>>>(Wv, Wv_t, DD, DD);
  prep_wt<<<(DD * DD + 255) / 256, 256, 0, stream>>>(Wo, Wo_t, DD, DD);
  prep_wt<<<(DD * HID + 255) / 256, 256, 0, stream>>>(W1, W1_t, DD, HID);   // in 768x192 -> out 192x768
  prep_wt<<<(HID * DD + 255) / 256, 256, 0, stream>>>(W2, W2_t, HID, DD);   // in 192x768 -> out 768x192
  wcat_kernel<<<(128 * DD + 255) / 256, 256, 0, stream>>>(Woff, Wattn, boff, battn, Wcat_t, bias_cat);

  // LayerNorms -> bf16
  ln_kernel<<<Mq, 256, 0, stream>>>(query, qn_g, qn_b, qn_bf);
  ln_kernel<<<Mf, 256, 0, stream>>>(feat, fn_g, fn_b, fn_bf);

  // value = fn @ Wv + bv  (bf16 out for sampler)
  gemm_bf16<128, 128, 2, 2, false, true><<<dim3(DD / 128, Mf / 128), 256, 0, stream>>>(
      fn_bf, Wv_t, bv, nullptr, val_bf, Mf, DD, DD);

  // off|logits = qn @ Wcat + bias_cat
  gemm_bf16<128, 128, 2, 2, false, false><<<dim3(1, Mq / 128), 256, 0, stream>>>(
      qn_bf, Wcat_t, bias_cat, nullptr, off, Mq, 128, DD);

  // softmax + coords
  meta_kernel<<<(Mq * 24 + 255) / 256, 256, 0, stream>>>(off, refp, meta);

  // bilinear sampling -> s (bf16)
  sample_kernel<<<Mq, 256, 0, stream>>>(val_bf, meta, s_bf);

  // q2 = query + s @ Wo + bo -> out (fp32)
  gemm_bf16<128, 128, 2, 2, true, false><<<dim3(DD / 128, Mq / 128), 256, 0, stream>>>(
      s_bf, Wo_t, bo, query, out, Mq, DD, DD);

  // ln2 = LN(q2) -> qn_bf (reuse)
  ln_kernel<<<Mq, 256, 0, stream>>>(out, ffn_g, ffn_b, qn_bf);

  // h = ln2 @ W1 + b1 (bf16 out)
  gemm_bf16<128, 64, 4, 1, false, true><<<dim3(HID / 64, Mq / 128), 256, 0, stream>>>(
      qn_bf, W1_t, b1, nullptr, h_bf, Mq, HID, DD);

  // depthwise conv + GELU (bf16 -> bf16)
  {
    size_t total = (size_t)BB * NN * HID;
    int blocks = (int)((total + 255) / 256);
    dwconv_gelu_kernel<<<blocks, 256, 0, stream>>>(h_bf, dw_w, dw_b, h2_bf);
  }

  // out = q2 + h2 @ W2 + b2 (in-place residual)
  gemm_bf16<128, 128, 2, 2, true, false><<<dim3(DD / 128, Mq / 128), 256, 0, stream>>>(
      h2_bf, W2_t, b2, out, out, Mq, DD, HID);
}

// Round 3
// 435.272 us; speedup vs baseline: 3.3078x; 1.0860x over previous
//
#include <hip/hip_runtime.h>
#include <math.h>

// Problem constants (B=2, Hs=Ws=48, D=768, heads=6, P=4)
#define BB 2
#define NN 12096     // 21 * (48*48/4)
#define LL 2304      // 48*48
#define DD 768
#define HID 192
#define HS 48
#define WS 48

typedef unsigned short u16;
typedef unsigned int u32;
typedef __attribute__((ext_vector_type(8))) __bf16 bf16x8;
typedef __attribute__((ext_vector_type(4))) float f32x4;

__device__ __forceinline__ u16 f2bf(float f) {
  u32 x = __builtin_bit_cast(u32, f);
  u32 r = (x + 0x7fffu + ((x >> 16) & 1u)) >> 16;  // RNE
  return (u16)r;
}
__device__ __forceinline__ float bf2f(u16 u) {
  u32 x = ((u32)u) << 16;
  return __builtin_bit_cast(float, x);
}

// ---------------- LayerNorm (templated input type): one block per row of 768, bf16 out ----------------
template <typename T>
__global__ __launch_bounds__(256) void ln_kernel(const T* __restrict__ x,
                                                 const float* __restrict__ g,
                                                 const float* __restrict__ bta,
                                                 u16* __restrict__ y) {
  size_t row = blockIdx.x;
  const T* xr = x + row * DD;
  int t = threadIdx.x;
  float v0, v1, v2;
  if constexpr (sizeof(T) == 2) {
    v0 = bf2f(xr[t]); v1 = bf2f(xr[t + 256]); v2 = bf2f(xr[t + 512]);
  } else {
    v0 = xr[t]; v1 = xr[t + 256]; v2 = xr[t + 512];
  }
  float s = v0 + v1 + v2;
  float s2 = v0 * v0 + v1 * v1 + v2 * v2;
#pragma unroll
  for (int off = 32; off; off >>= 1) {
    s += __shfl_down(s, off, 64);
    s2 += __shfl_down(s2, off, 64);
  }
  __shared__ float red[8];
  __shared__ float mv[2];
  int wave = t >> 6, lane = t & 63;
  if (lane == 0) { red[wave] = s; red[4 + wave] = s2; }
  __syncthreads();
  if (t == 0) {
    float ts = red[0] + red[1] + red[2] + red[3];
    float ts2 = red[4] + red[5] + red[6] + red[7];
    float m = ts * (1.f / DD);
    float var = ts2 * (1.f / DD) - m * m;
    mv[0] = m;
    mv[1] = rsqrtf(var + 1e-6f);
  }
  __syncthreads();
  float m = mv[0], rs = mv[1];
  u16* yr = y + row * DD;
  yr[t]       = f2bf((v0 - m) * rs * g[t]       + bta[t]);
  yr[t + 256] = f2bf((v1 - m) * rs * g[t + 256] + bta[t + 256]);
  yr[t + 512] = f2bf((v2 - m) * rs * g[t + 512] + bta[t + 512]);
}

// ---------------- bf16 MFMA GEMM ----------------
// C(MxN) = A(MxK)bf16 @ Bt(NxK)bf16 + bias (+res).
// RES: 0 none, 1 fp32, 2 bf16. OUT: 0 fp32, 1 bf16.
// NTSW: 0 -> plain 2D grid; else 1D grid with XCD-aware swizzle, NTSW = n-tile count.
// LDS XOR-swizzle: LDS[row][lq] = global[row][lq ^ (row&7)] in 16B chunks (global_load_lds
// forbids padding; swizzle keeps ds_read_b128 at 2-way bank aliasing = free).
template <int BM, int BN, int WM, int WN, int RES, int OUT, int NTSW>
__global__ __launch_bounds__(256, 2) void gemm_bf16(const u16* __restrict__ A,
                                                    const u16* __restrict__ Bt,
                                                    const float* __restrict__ bias,
                                                    const void* __restrict__ res,
                                                    void* __restrict__ Cv,
                                                    int M, int N, int K) {
  constexpr int PM = BM / WM, PN = BN / WN;
  constexpr int FM = PM / 16, FN = PN / 16;
  constexpr int ASEG = BM / 32;
  constexpr int BSEG = BN / 32;
  int bx, by;
  if (NTSW > 0) {
    int flat = blockIdx.x;
    int x = flat & 7, gidx = flat >> 3;
    bx = gidx % NTSW;
    int mg = gidx / NTSW;
    by = mg * 8 + x;
    if (by * BM >= M) return;
  } else {
    bx = blockIdx.x;
    by = blockIdx.y;
  }
  __shared__ u16 As[BM * 64];
  __shared__ u16 Bs[BN * 64];
  int tid = threadIdx.x;
  int w = tid >> 6, lane = tid & 63;
  int rw = w / WN, cw = w % WN;
  int m0 = by * BM, n0 = bx * BN;

  f32x4 acc[FM][FN];
#pragma unroll
  for (int i = 0; i < FM; ++i)
#pragma unroll
    for (int j = 0; j < FN; ++j) acc[i][j] = (f32x4){0.f, 0.f, 0.f, 0.f};

  int lr = lane >> 3;
  int lq = lane & 7;
  int qg = lq ^ lr;
  int l15 = lane & 15, quad = lane >> 4;

  for (int k0 = 0; k0 < K; k0 += 64) {
#pragma unroll
    for (int i = 0; i < ASEG; ++i) {
      int s = w * ASEG + i;
      int row = s * 8 + lr;
      const u16* gp = A + (size_t)(m0 + row) * K + k0 + qg * 8;
      __builtin_amdgcn_global_load_lds(
          (const __attribute__((address_space(1))) void*)gp,
          (__attribute__((address_space(3))) void*)&As[s * 512], 16, 0, 0);
    }
#pragma unroll
    for (int i = 0; i < BSEG; ++i) {
      int s = w * BSEG + i;
      int row = s * 8 + lr;
      const u16* gp = Bt + (size_t)(n0 + row) * K + k0 + qg * 8;
      __builtin_amdgcn_global_load_lds(
          (const __attribute__((address_space(1))) void*)gp,
          (__attribute__((address_space(3))) void*)&Bs[s * 512], 16, 0, 0);
    }
    __syncthreads();
#pragma unroll
    for (int s2 = 0; s2 < 2; ++s2) {
      bf16x8 af[FM], bfr[FN];
#pragma unroll
      for (int mt = 0; mt < FM; ++mt) {
        int rm = rw * PM + mt * 16 + l15;
        int ch = (s2 * 4 + quad) ^ (rm & 7);
        af[mt] = *(const bf16x8*)&As[rm * 64 + ch * 8];
      }
#pragma unroll
      for (int nt = 0; nt < FN; ++nt) {
        int rn = cw * PN + nt * 16 + l15;
        int ch = (s2 * 4 + quad) ^ (rn & 7);
        bfr[nt] = *(const bf16x8*)&Bs[rn * 64 + ch * 8];
      }
#pragma unroll
      for (int mt = 0; mt < FM; ++mt)
#pragma unroll
        for (int nt = 0; nt < FN; ++nt)
          acc[mt][nt] = __builtin_amdgcn_mfma_f32_16x16x32_bf16(af[mt], bfr[nt], acc[mt][nt], 0, 0, 0);
    }
    __syncthreads();
  }

#pragma unroll
  for (int mt = 0; mt < FM; ++mt) {
    int m = m0 + rw * PM + mt * 16 + quad * 4;
#pragma unroll
    for (int nt = 0; nt < FN; ++nt) {
      int n = n0 + cw * PN + nt * 16 + l15;
      float bsv = bias[n];
#pragma unroll
      for (int r = 0; r < 4; ++r) {
        size_t idx = (size_t)(m + r) * N + n;
        float v = acc[mt][nt][r] + bsv;
        if (RES == 1) v += ((const float*)res)[idx];
        if (RES == 2) v += bf2f(((const u16*)res)[idx]);
        if (OUT == 1) ((u16*)Cv)[idx] = f2bf(v);
        else ((float*)Cv)[idx] = v;
      }
    }
  }
}

// ---------------- merged weight prep (all transposes + concat) ----------------
#define PREP_B0 (DD * DD)            // Wv_t
#define PREP_B1 (2 * DD * DD)        // Wo_t
#define PREP_B2 (PREP_B1 + HID * DD) // W1_t (192x768)
#define PREP_B3 (PREP_B2 + HID * DD) // W2_t (768x192)
#define PREP_B4 (PREP_B3 + 128 * DD) // Wcat_t
__global__ __launch_bounds__(256) void prep_all(const float* __restrict__ Wv, const float* __restrict__ Wo,
                                                const float* __restrict__ W1, const float* __restrict__ W2,
                                                const float* __restrict__ Woff, const float* __restrict__ Wattn,
                                                const float* __restrict__ boff, const float* __restrict__ battn,
                                                u16* __restrict__ Wv_t, u16* __restrict__ Wo_t,
                                                u16* __restrict__ W1_t, u16* __restrict__ W2_t,
                                                u16* __restrict__ Wcat_t, float* __restrict__ bias_cat) {
  int idx = blockIdx.x * 256 + threadIdx.x;
  if (idx >= PREP_B4) return;
  if (idx < PREP_B0) {
    int n = idx / DD, k = idx - n * DD;
    Wv_t[idx] = f2bf(Wv[(size_t)k * DD + n]);
  } else if (idx < PREP_B1) {
    int l = idx - PREP_B0;
    int n = l / DD, k = l - n * DD;
    Wo_t[l] = f2bf(Wo[(size_t)k * DD + n]);
  } else if (idx < PREP_B2) {
    int l = idx - PREP_B1;                 // out: 192 x 768
    int n = l / DD, k = l - n * DD;
    W1_t[l] = f2bf(W1[(size_t)k * HID + n]);
  } else if (idx < PREP_B3) {
    int l = idx - PREP_B2;                 // out: 768 x 192
    int n = l / HID, k = l - n * HID;
    W2_t[l] = f2bf(W2[(size_t)k * DD + n]);
  } else {
    int l = idx - PREP_B3;                 // out: 128 x 768
    int n = l / DD, k = l - n * DD;
    float v = 0.f;
    if (n < 48) v = Woff[(size_t)k * 48 + n];
    else if (n < 72) v = Wattn[(size_t)k * 24 + (n - 48)];
    Wcat_t[l] = f2bf(v);
    if (l < 128) {
      float b = 0.f;
      if (l < 48) b = boff[l];
      else if (l < 72) b = battn[l - 48];
      bias_cat[l] = b;
    }
  }
}

// ---------------- fused softmax + bilinear sampling (192 threads = 3 waves) ----------------
__global__ __launch_bounds__(192) void sample_kernel(const u16* __restrict__ value,
                                                     const float* __restrict__ off,
                                                     const float* __restrict__ refp,
                                                     u16* __restrict__ s) {
  size_t row = blockIdx.x;  // b*N + n
  int b = (int)(row / NN);
  __shared__ int cidx[96];
  __shared__ float cw[96];
  int t = threadIdx.x;
  if (t < 24) {
    const float* o = off + row * 128;
    int hh = t >> 2, p = t & 3;
    float l0 = o[48 + hh * 4 + 0], l1 = o[48 + hh * 4 + 1];
    float l2 = o[48 + hh * 4 + 2], l3 = o[48 + hh * 4 + 3];
    float mx = fmaxf(fmaxf(l0, l1), fmaxf(l2, l3));
    float e0 = expf(l0 - mx), e1 = expf(l1 - mx), e2 = expf(l2 - mx), e3 = expf(l3 - mx);
    float sum = e0 + e1 + e2 + e3;
    float et = (p == 0) ? e0 : (p == 1) ? e1 : (p == 2) ? e2 : e3;
    float aw = et / sum;
    float x = refp[row * 2 + 0] * (float)WS - 0.5f + o[hh * 8 + p * 2 + 0];
    float y = refp[row * 2 + 1] * (float)HS - 0.5f + o[hh * 8 + p * 2 + 1];
    float xf = floorf(x), yf = floorf(y);
    int x0 = (int)xf, y0 = (int)yf;
    float wx = x - xf, wy = y - yf;
#pragma unroll
    for (int c = 0; c < 4; ++c) {
      int xi = x0 + (c & 1), yi = y0 + (c >> 1);
      float w = ((c & 1) ? wx : 1.f - wx) * ((c >> 1) ? wy : 1.f - wy);
      bool valid = (xi >= 0) && (xi < WS) && (yi >= 0) && (yi < HS);
      int xc = min(max(xi, 0), WS - 1), yc = min(max(yi, 0), HS - 1);
      cidx[t * 4 + c] = yc * WS + xc;
      cw[t * 4 + c] = valid ? w * aw : 0.f;
    }
  }
  __syncthreads();
  const u16* vb = value + (size_t)b * LL * DD;
  int c = t * 4;       // 192 threads x 4 channels = 768
  int h = c >> 7;
  float a0 = 0.f, a1 = 0.f, a2 = 0.f, a3 = 0.f;
#pragma unroll
  for (int pp = 0; pp < 4; ++pp) {
    int base = (h * 4 + pp) * 4;
#pragma unroll
    for (int cc = 0; cc < 4; ++cc) {
      float w = cw[base + cc];
      ushort4 v = *(const ushort4*)&vb[(size_t)cidx[base + cc] * DD + c];
      a0 += w * bf2f(v.x);
      a1 += w * bf2f(v.y);
      a2 += w * bf2f(v.z);
      a3 += w * bf2f(v.w);
    }
  }
  ushort4 o4;
  o4.x = f2bf(a0); o4.y = f2bf(a1); o4.z = f2bf(a2); o4.w = f2bf(a3);
  *(ushort4*)&s[row * DD + c] = o4;
}

// ---------------- depthwise 3x3 (3 scales) + exact GELU, bf16 in/out ----------------
__global__ __launch_bounds__(256) void dwconv_gelu_kernel(const u16* __restrict__ h,
                                                          const float* __restrict__ w,
                                                          const float* __restrict__ bias,
                                                          u16* __restrict__ out) {
  size_t idx = (size_t)blockIdx.x * 256 + threadIdx.x;
  if (idx >= (size_t)BB * NN * HID) return;
  int c = (int)(idx % HID);
  int rem = (int)(idx / HID);
  int nidx = rem % NN;
  int b = rem / NN;
  int hh, ww, base;
  if (nidx < 9216)       { hh = 96; ww = 96; base = 0; }
  else if (nidx < 11520) { hh = 48; ww = 48; base = 9216; }
  else                   { hh = 24; ww = 24; base = 11520; }
  int p = nidx - base;
  int y = p / ww, x = p % ww;
  const u16* hb = h + ((size_t)b * NN + base) * HID;
  float acc = bias[c];
#pragma unroll
  for (int dy = -1; dy <= 1; ++dy) {
    int yy = y + dy;
    if (yy < 0 || yy >= hh) continue;
#pragma unroll
    for (int dx = -1; dx <= 1; ++dx) {
      int xx = x + dx;
      if (xx < 0 || xx >= ww) continue;
      acc += bf2f(hb[((size_t)(yy * ww + xx)) * HID + c]) * w[c * 9 + (dy + 1) * 3 + (dx + 1)];
    }
  }
  float g = 0.5f * acc * (1.f + erff(acc * 0.70710678118654752f));
  out[idx] = f2bf(g);
}

extern "C" void kernel_launch(void* const* d_in, const int* in_sizes, int n_in,
                              void* d_out, int out_size, void* d_ws, size_t ws_size,
                              hipStream_t stream) {
  const float* query = (const float*)d_in[0];
  const float* refp  = (const float*)d_in[1];
  const float* feat  = (const float*)d_in[2];
  const float* qn_g  = (const float*)d_in[7];
  const float* qn_b  = (const float*)d_in[8];
  const float* fn_g  = (const float*)d_in[9];
  const float* fn_b  = (const float*)d_in[10];
  const float* Wv    = (const float*)d_in[11];
  const float* bv    = (const float*)d_in[12];
  const float* Woff  = (const float*)d_in[13];
  const float* boff  = (const float*)d_in[14];
  const float* Wattn = (const float*)d_in[15];
  const float* battn = (const float*)d_in[16];
  const float* Wo    = (const float*)d_in[17];
  const float* bo    = (const float*)d_in[18];
  const float* ffn_g = (const float*)d_in[19];
  const float* ffn_b = (const float*)d_in[20];
  const float* W1    = (const float*)d_in[21];
  const float* b1    = (const float*)d_in[22];
  const float* dw_w  = (const float*)d_in[23];
  const float* dw_b  = (const float*)d_in[24];
  const float* W2    = (const float*)d_in[25];
  const float* b2    = (const float*)d_in[26];
  float* out = (float*)d_out;

  const int Mq = BB * NN;  // 24192
  const int Mf = BB * LL;  // 4608

  char* p = (char*)d_ws;
  auto alloc = [&](size_t bytes) { char* r = p; p += (bytes + 255) & ~(size_t)255; return r; };
  u16* qn_bf   = (u16*)alloc((size_t)Mq * DD * 2);   // reused for ln2
  u16* fn_bf   = (u16*)alloc((size_t)Mf * DD * 2);
  u16* val_bf  = (u16*)alloc((size_t)Mf * DD * 2);
  float* off   = (float*)alloc((size_t)Mq * 128 * 4);
  u16* s_bf    = (u16*)alloc((size_t)Mq * DD * 2);
  u16* q2_bf   = (u16*)alloc((size_t)Mq * DD * 2);
  u16* h_bf    = (u16*)alloc((size_t)Mq * HID * 2);
  u16* h2_bf   = (u16*)alloc((size_t)Mq * HID * 2);
  u16* Wv_t    = (u16*)alloc((size_t)DD * DD * 2);
  u16* Wo_t    = (u16*)alloc((size_t)DD * DD * 2);
  u16* W1_t    = (u16*)alloc((size_t)HID * DD * 2);
  u16* W2_t    = (u16*)alloc((size_t)DD * HID * 2);
  u16* Wcat_t  = (u16*)alloc((size_t)128 * DD * 2);
  float* bias_cat = (float*)alloc(128 * 4);

  // merged weight prep
  prep_all<<<(PREP_B4 + 255) / 256, 256, 0, stream>>>(Wv, Wo, W1, W2, Woff, Wattn, boff, battn,
                                                      Wv_t, Wo_t, W1_t, W2_t, Wcat_t, bias_cat);

  // LayerNorms -> bf16
  ln_kernel<float><<<Mq, 256, 0, stream>>>(query, qn_g, qn_b, qn_bf);
  ln_kernel<float><<<Mf, 256, 0, stream>>>(feat, fn_g, fn_b, fn_bf);

  // value = fn @ Wv + bv (bf16)
  gemm_bf16<64, 256, 1, 4, 0, 1, 0><<<dim3(DD / 256, Mf / 64), 256, 0, stream>>>(
      fn_bf, Wv_t, bv, nullptr, val_bf, Mf, DD, DD);

  // off|logits = qn @ Wcat + bias_cat (fp32)
  gemm_bf16<64, 128, 2, 2, 0, 0, 0><<<dim3(1, Mq / 64), 256, 0, stream>>>(
      qn_bf, Wcat_t, bias_cat, nullptr, off, Mq, 128, DD);

  // fused softmax + bilinear sampling -> s (bf16)
  sample_kernel<<<Mq, 192, 0, stream>>>(val_bf, off, refp, s_bf);

  // q2 = query + s @ Wo + bo -> bf16, XCD-swizzled grid (189 m-tiles, 3 n-tiles)
  gemm_bf16<128, 256, 2, 2, 1, 1, 3><<<((Mq / 128 + 7) / 8) * 8 * 3, 256, 0, stream>>>(
      s_bf, Wo_t, bo, query, q2_bf, Mq, DD, DD);

  // ln2 = LN(q2_bf) -> qn_bf (reuse)
  ln_kernel<u16><<<Mq, 256, 0, stream>>>(q2_bf, ffn_g, ffn_b, qn_bf);

  // h = ln2 @ W1 + b1 (bf16)
  gemm_bf16<64, 192, 1, 4, 0, 1, 0><<<dim3(1, Mq / 64), 256, 0, stream>>>(
      qn_bf, W1_t, b1, nullptr, h_bf, Mq, HID, DD);

  // depthwise conv + GELU
  {
    size_t total = (size_t)BB * NN * HID;
    int blocks = (int)((total + 255) / 256);
    dwconv_gelu_kernel<<<blocks, 256, 0, stream>>>(h_bf, dw_w, dw_b, h2_bf);
  }

  // out = q2 + h2 @ W2 + b2 (fp32 final), XCD-swizzled grid
  gemm_bf16<128, 256, 2, 2, 2, 0, 3><<<((Mq / 128 + 7) / 8) * 8 * 3, 256, 0, stream>>>(
      h2_bf, W2_t, b2, q2_bf, out, Mq, DD, HID);
}

// Round 4
// 414.008 us; speedup vs baseline: 3.4777x; 1.0514x over previous
//
#include <hip/hip_runtime.h>
#include <math.h>

// Problem constants (B=2, Hs=Ws=48, D=768, heads=6, P=4)
#define BB 2
#define NN 12096     // 21 * (48*48/4)
#define LL 2304      // 48*48
#define DD 768
#define HID 192
#define HS 48
#define WS 48

typedef unsigned short u16;
typedef unsigned int u32;
typedef __attribute__((ext_vector_type(8))) __bf16 bf16x8;
typedef __attribute__((ext_vector_type(4))) float f32x4;

__device__ __forceinline__ u16 f2bf(float f) {
  u32 x = __builtin_bit_cast(u32, f);
  u32 r = (x + 0x7fffu + ((x >> 16) & 1u)) >> 16;  // RNE
  return (u16)r;
}
__device__ __forceinline__ float bf2f(u16 u) {
  u32 x = ((u32)u) << 16;
  return __builtin_bit_cast(float, x);
}

// ---------------- LayerNorm body ----------------
template <typename T>
__device__ __forceinline__ void ln_row(const T* xr, const float* g, const float* bta, u16* yr, int t) {
  float v0, v1, v2;
  if constexpr (sizeof(T) == 2) {
    v0 = bf2f(xr[t]); v1 = bf2f(xr[t + 256]); v2 = bf2f(xr[t + 512]);
  } else {
    v0 = xr[t]; v1 = xr[t + 256]; v2 = xr[t + 512];
  }
  float s = v0 + v1 + v2;
  float s2 = v0 * v0 + v1 * v1 + v2 * v2;
#pragma unroll
  for (int off = 32; off; off >>= 1) {
    s += __shfl_down(s, off, 64);
    s2 += __shfl_down(s2, off, 64);
  }
  __shared__ float red[8];
  __shared__ float mv[2];
  int wave = t >> 6, lane = t & 63;
  if (lane == 0) { red[wave] = s; red[4 + wave] = s2; }
  __syncthreads();
  if (t == 0) {
    float ts = red[0] + red[1] + red[2] + red[3];
    float ts2 = red[4] + red[5] + red[6] + red[7];
    float m = ts * (1.f / DD);
    float var = ts2 * (1.f / DD) - m * m;
    mv[0] = m;
    mv[1] = rsqrtf(var + 1e-6f);
  }
  __syncthreads();
  float m = mv[0], rs = mv[1];
  yr[t]       = f2bf((v0 - m) * rs * g[t]       + bta[t]);
  yr[t + 256] = f2bf((v1 - m) * rs * g[t + 256] + bta[t + 256]);
  yr[t + 512] = f2bf((v2 - m) * rs * g[t + 512] + bta[t + 512]);
}

template <typename T>
__global__ __launch_bounds__(256) void ln_kernel(const T* __restrict__ x,
                                                 const float* __restrict__ g,
                                                 const float* __restrict__ bta,
                                                 u16* __restrict__ y) {
  size_t row = blockIdx.x;
  ln_row<T>(x + row * DD, g, bta, y + row * DD, threadIdx.x);
}

// merged LN for query (Mq rows) and feat (Mf rows), both fp32
__global__ __launch_bounds__(256) void ln_dual_kernel(const float* __restrict__ xq,
                                                      const float* __restrict__ gq,
                                                      const float* __restrict__ bq,
                                                      u16* __restrict__ yq,
                                                      const float* __restrict__ xf,
                                                      const float* __restrict__ gf,
                                                      const float* __restrict__ bf_,
                                                      u16* __restrict__ yf,
                                                      int Mq) {
  size_t row = blockIdx.x;
  if (row < (size_t)Mq)
    ln_row<float>(xq + row * DD, gq, bq, yq + row * DD, threadIdx.x);
  else {
    size_t r = row - Mq;
    ln_row<float>(xf + r * DD, gf, bf_, yf + r * DD, threadIdx.x);
  }
}

// ---------------- bf16 MFMA GEMM ----------------
// C(MxN) = A(MxK)bf16 @ Bt(NxK)bf16 + bias (+res).
// RES: 0 none, 1 fp32, 2 bf16. OUT: 0 fp32, 1 bf16.
// NTSW: 0 -> plain 2D grid; else 1D grid with XCD-aware swizzle (NTSW = n-tile count):
// the NTSW n-tiles of one m-tile are placed at consecutive grid slots with the same
// (flat & 7) so they dispatch to the same XCD and share the A m-tile via that XCD's L2.
template <int BM, int BN, int WM, int WN, int RES, int OUT, int NTSW>
__global__ __launch_bounds__(256, 2) void gemm_bf16(const u16* __restrict__ A,
                                                    const u16* __restrict__ Bt,
                                                    const float* __restrict__ bias,
                                                    const void* __restrict__ res,
                                                    void* __restrict__ Cv,
                                                    int M, int N, int K) {
  constexpr int PM = BM / WM, PN = BN / WN;
  constexpr int FM = PM / 16, FN = PN / 16;
  constexpr int ASEG = BM / 32;
  constexpr int BSEG = BN / 32;
  int bx, by;
  if (NTSW > 0) {
    int flat = blockIdx.x;
    int x = flat & 7, gidx = flat >> 3;
    bx = gidx % NTSW;
    int mg = gidx / NTSW;
    by = mg * 8 + x;
    if (by * BM >= M) return;
  } else {
    bx = blockIdx.x;
    by = blockIdx.y;
  }
  __shared__ u16 As[BM * 64];
  __shared__ u16 Bs[BN * 64];
  int tid = threadIdx.x;
  int w = tid >> 6, lane = tid & 63;
  int rw = w / WN, cw = w % WN;
  int m0 = by * BM, n0 = bx * BN;

  f32x4 acc[FM][FN];
#pragma unroll
  for (int i = 0; i < FM; ++i)
#pragma unroll
    for (int j = 0; j < FN; ++j) acc[i][j] = (f32x4){0.f, 0.f, 0.f, 0.f};

  int lr = lane >> 3;
  int lq = lane & 7;
  int qg = lq ^ lr;
  int l15 = lane & 15, quad = lane >> 4;

  for (int k0 = 0; k0 < K; k0 += 64) {
#pragma unroll
    for (int i = 0; i < ASEG; ++i) {
      int s = w * ASEG + i;
      int row = s * 8 + lr;
      const u16* gp = A + (size_t)(m0 + row) * K + k0 + qg * 8;
      __builtin_amdgcn_global_load_lds(
          (const __attribute__((address_space(1))) void*)gp,
          (__attribute__((address_space(3))) void*)&As[s * 512], 16, 0, 0);
    }
#pragma unroll
    for (int i = 0; i < BSEG; ++i) {
      int s = w * BSEG + i;
      int row = s * 8 + lr;
      const u16* gp = Bt + (size_t)(n0 + row) * K + k0 + qg * 8;
      __builtin_amdgcn_global_load_lds(
          (const __attribute__((address_space(1))) void*)gp,
          (__attribute__((address_space(3))) void*)&Bs[s * 512], 16, 0, 0);
    }
    __syncthreads();
#pragma unroll
    for (int s2 = 0; s2 < 2; ++s2) {
      bf16x8 af[FM], bfr[FN];
#pragma unroll
      for (int mt = 0; mt < FM; ++mt) {
        int rm = rw * PM + mt * 16 + l15;
        int ch = (s2 * 4 + quad) ^ (rm & 7);
        af[mt] = *(const bf16x8*)&As[rm * 64 + ch * 8];
      }
#pragma unroll
      for (int nt = 0; nt < FN; ++nt) {
        int rn = cw * PN + nt * 16 + l15;
        int ch = (s2 * 4 + quad) ^ (rn & 7);
        bfr[nt] = *(const bf16x8*)&Bs[rn * 64 + ch * 8];
      }
#pragma unroll
      for (int mt = 0; mt < FM; ++mt)
#pragma unroll
        for (int nt = 0; nt < FN; ++nt)
          acc[mt][nt] = __builtin_amdgcn_mfma_f32_16x16x32_bf16(af[mt], bfr[nt], acc[mt][nt], 0, 0, 0);
    }
    __syncthreads();
  }

#pragma unroll
  for (int mt = 0; mt < FM; ++mt) {
    int m = m0 + rw * PM + mt * 16 + quad * 4;
#pragma unroll
    for (int nt = 0; nt < FN; ++nt) {
      int n = n0 + cw * PN + nt * 16 + l15;
      float bsv = bias[n];
#pragma unroll
      for (int r = 0; r < 4; ++r) {
        size_t idx = (size_t)(m + r) * N + n;
        float v = acc[mt][nt][r] + bsv;
        if (RES == 1) v += ((const float*)res)[idx];
        if (RES == 2) v += bf2f(((const u16*)res)[idx]);
        if (OUT == 1) ((u16*)Cv)[idx] = f2bf(v);
        else ((float*)Cv)[idx] = v;
      }
    }
  }
}

// ---------------- merged weight prep (all transposes + concat) ----------------
#define PREP_B0 (DD * DD)            // Wv_t
#define PREP_B1 (2 * DD * DD)        // Wo_t
#define PREP_B2 (PREP_B1 + HID * DD) // W1_t (192x768)
#define PREP_B3 (PREP_B2 + HID * DD) // W2_t (768x192)
#define PREP_B4 (PREP_B3 + 128 * DD) // Wcat_t
__global__ __launch_bounds__(256) void prep_all(const float* __restrict__ Wv, const float* __restrict__ Wo,
                                                const float* __restrict__ W1, const float* __restrict__ W2,
                                                const float* __restrict__ Woff, const float* __restrict__ Wattn,
                                                const float* __restrict__ boff, const float* __restrict__ battn,
                                                u16* __restrict__ Wv_t, u16* __restrict__ Wo_t,
                                                u16* __restrict__ W1_t, u16* __restrict__ W2_t,
                                                u16* __restrict__ Wcat_t, float* __restrict__ bias_cat) {
  int idx = blockIdx.x * 256 + threadIdx.x;
  if (idx >= PREP_B4) return;
  if (idx < PREP_B0) {
    int n = idx / DD, k = idx - n * DD;
    Wv_t[idx] = f2bf(Wv[(size_t)k * DD + n]);
  } else if (idx < PREP_B1) {
    int l = idx - PREP_B0;
    int n = l / DD, k = l - n * DD;
    Wo_t[l] = f2bf(Wo[(size_t)k * DD + n]);
  } else if (idx < PREP_B2) {
    int l = idx - PREP_B1;                 // out: 192 x 768
    int n = l / DD, k = l - n * DD;
    W1_t[l] = f2bf(W1[(size_t)k * HID + n]);
  } else if (idx < PREP_B3) {
    int l = idx - PREP_B2;                 // out: 768 x 192
    int n = l / HID, k = l - n * HID;
    W2_t[l] = f2bf(W2[(size_t)k * DD + n]);
  } else {
    int l = idx - PREP_B3;                 // out: 128 x 768
    int n = l / DD, k = l - n * DD;
    float v = 0.f;
    if (n < 48) v = Woff[(size_t)k * 48 + n];
    else if (n < 72) v = Wattn[(size_t)k * 24 + (n - 48)];
    Wcat_t[l] = f2bf(v);
    if (l < 128) {
      float b = 0.f;
      if (l < 48) b = boff[l];
      else if (l < 72) b = battn[l - 48];
      bias_cat[l] = b;
    }
  }
}

// ---------------- fused softmax + bilinear sampling (192 threads = 3 waves) ----------------
__global__ __launch_bounds__(192) void sample_kernel(const u16* __restrict__ value,
                                                     const float* __restrict__ off,
                                                     const float* __restrict__ refp,
                                                     u16* __restrict__ s) {
  size_t row = blockIdx.x;  // b*N + n
  int b = (int)(row / NN);
  __shared__ int cidx[96];
  __shared__ float cw[96];
  int t = threadIdx.x;
  if (t < 24) {
    const float* o = off + row * 128;
    int hh = t >> 2, p = t & 3;
    float l0 = o[48 + hh * 4 + 0], l1 = o[48 + hh * 4 + 1];
    float l2 = o[48 + hh * 4 + 2], l3 = o[48 + hh * 4 + 3];
    float mx = fmaxf(fmaxf(l0, l1), fmaxf(l2, l3));
    float e0 = expf(l0 - mx), e1 = expf(l1 - mx), e2 = expf(l2 - mx), e3 = expf(l3 - mx);
    float sum = e0 + e1 + e2 + e3;
    float et = (p == 0) ? e0 : (p == 1) ? e1 : (p == 2) ? e2 : e3;
    float aw = et / sum;
    float x = refp[row * 2 + 0] * (float)WS - 0.5f + o[hh * 8 + p * 2 + 0];
    float y = refp[row * 2 + 1] * (float)HS - 0.5f + o[hh * 8 + p * 2 + 1];
    float xf = floorf(x), yf = floorf(y);
    int x0 = (int)xf, y0 = (int)yf;
    float wx = x - xf, wy = y - yf;
#pragma unroll
    for (int c = 0; c < 4; ++c) {
      int xi = x0 + (c & 1), yi = y0 + (c >> 1);
      float w = ((c & 1) ? wx : 1.f - wx) * ((c >> 1) ? wy : 1.f - wy);
      bool valid = (xi >= 0) && (xi < WS) && (yi >= 0) && (yi < HS);
      int xc = min(max(xi, 0), WS - 1), yc = min(max(yi, 0), HS - 1);
      cidx[t * 4 + c] = yc * WS + xc;
      cw[t * 4 + c] = valid ? w * aw : 0.f;
    }
  }
  __syncthreads();
  const u16* vb = value + (size_t)b * LL * DD;
  int c = t * 4;       // 192 threads x 4 channels = 768
  int h = c >> 7;
  float a0 = 0.f, a1 = 0.f, a2 = 0.f, a3 = 0.f;
#pragma unroll
  for (int pp = 0; pp < 4; ++pp) {
    int base = (h * 4 + pp) * 4;
#pragma unroll
    for (int cc = 0; cc < 4; ++cc) {
      float w = cw[base + cc];
      ushort4 v = *(const ushort4*)&vb[(size_t)cidx[base + cc] * DD + c];
      a0 += w * bf2f(v.x);
      a1 += w * bf2f(v.y);
      a2 += w * bf2f(v.z);
      a3 += w * bf2f(v.w);
    }
  }
  ushort4 o4;
  o4.x = f2bf(a0); o4.y = f2bf(a1); o4.z = f2bf(a2); o4.w = f2bf(a3);
  *(ushort4*)&s[row * DD + c] = o4;
}

// ---------------- depthwise 3x3 (3 scales) + exact GELU, bf16 in/out ----------------
__global__ __launch_bounds__(256) void dwconv_gelu_kernel(const u16* __restrict__ h,
                                                          const float* __restrict__ w,
                                                          const float* __restrict__ bias,
                                                          u16* __restrict__ out) {
  size_t idx = (size_t)blockIdx.x * 256 + threadIdx.x;
  if (idx >= (size_t)BB * NN * HID) return;
  int c = (int)(idx % HID);
  int rem = (int)(idx / HID);
  int nidx = rem % NN;
  int b = rem / NN;
  int hh, ww, base;
  if (nidx < 9216)       { hh = 96; ww = 96; base = 0; }
  else if (nidx < 11520) { hh = 48; ww = 48; base = 9216; }
  else                   { hh = 24; ww = 24; base = 11520; }
  int p = nidx - base;
  int y = p / ww, x = p % ww;
  const u16* hb = h + ((size_t)b * NN + base) * HID;
  float acc = bias[c];
#pragma unroll
  for (int dy = -1; dy <= 1; ++dy) {
    int yy = y + dy;
    if (yy < 0 || yy >= hh) continue;
#pragma unroll
    for (int dx = -1; dx <= 1; ++dx) {
      int xx = x + dx;
      if (xx < 0 || xx >= ww) continue;
      acc += bf2f(hb[((size_t)(yy * ww + xx)) * HID + c]) * w[c * 9 + (dy + 1) * 3 + (dx + 1)];
    }
  }
  float g = 0.5f * acc * (1.f + erff(acc * 0.70710678118654752f));
  out[idx] = f2bf(g);
}

extern "C" void kernel_launch(void* const* d_in, const int* in_sizes, int n_in,
                              void* d_out, int out_size, void* d_ws, size_t ws_size,
                              hipStream_t stream) {
  const float* query = (const float*)d_in[0];
  const float* refp  = (const float*)d_in[1];
  const float* feat  = (const float*)d_in[2];
  const float* qn_g  = (const float*)d_in[7];
  const float* qn_b  = (const float*)d_in[8];
  const float* fn_g  = (const float*)d_in[9];
  const float* fn_b  = (const float*)d_in[10];
  const float* Wv    = (const float*)d_in[11];
  const float* bv    = (const float*)d_in[12];
  const float* Woff  = (const float*)d_in[13];
  const float* boff  = (const float*)d_in[14];
  const float* Wattn = (const float*)d_in[15];
  const float* battn = (const float*)d_in[16];
  const float* Wo    = (const float*)d_in[17];
  const float* bo    = (const float*)d_in[18];
  const float* ffn_g = (const float*)d_in[19];
  const float* ffn_b = (const float*)d_in[20];
  const float* W1    = (const float*)d_in[21];
  const float* b1    = (const float*)d_in[22];
  const float* dw_w  = (const float*)d_in[23];
  const float* dw_b  = (const float*)d_in[24];
  const float* W2    = (const float*)d_in[25];
  const float* b2    = (const float*)d_in[26];
  float* out = (float*)d_out;

  const int Mq = BB * NN;  // 24192
  const int Mf = BB * LL;  // 4608

  char* p = (char*)d_ws;
  auto alloc = [&](size_t bytes) { char* r = p; p += (bytes + 255) & ~(size_t)255; return r; };
  u16* qn_bf   = (u16*)alloc((size_t)Mq * DD * 2);   // reused for ln2
  u16* fn_bf   = (u16*)alloc((size_t)Mf * DD * 2);
  u16* val_bf  = (u16*)alloc((size_t)Mf * DD * 2);
  float* off   = (float*)alloc((size_t)Mq * 128 * 4);
  u16* s_bf    = (u16*)alloc((size_t)Mq * DD * 2);
  u16* q2_bf   = (u16*)alloc((size_t)Mq * DD * 2);
  u16* h_bf    = (u16*)alloc((size_t)Mq * HID * 2);
  u16* h2_bf   = (u16*)alloc((size_t)Mq * HID * 2);
  u16* Wv_t    = (u16*)alloc((size_t)DD * DD * 2);
  u16* Wo_t    = (u16*)alloc((size_t)DD * DD * 2);
  u16* W1_t    = (u16*)alloc((size_t)HID * DD * 2);
  u16* W2_t    = (u16*)alloc((size_t)DD * HID * 2);
  u16* Wcat_t  = (u16*)alloc((size_t)128 * DD * 2);
  float* bias_cat = (float*)alloc(128 * 4);

  // merged weight prep
  prep_all<<<(PREP_B4 + 255) / 256, 256, 0, stream>>>(Wv, Wo, W1, W2, Woff, Wattn, boff, battn,
                                                      Wv_t, Wo_t, W1_t, W2_t, Wcat_t, bias_cat);

  // LayerNorms (query + feat) -> bf16, one launch
  ln_dual_kernel<<<Mq + Mf, 256, 0, stream>>>(query, qn_g, qn_b, qn_bf, feat, fn_g, fn_b, fn_bf, Mq);

  // value = fn @ Wv + bv (bf16), XCD-swizzled (36 m-tiles, 6 n-tiles)
  gemm_bf16<128, 128, 2, 2, 0, 1, 6><<<((Mf / 128 + 7) / 8) * 8 * 6, 256, 0, stream>>>(
      fn_bf, Wv_t, bv, nullptr, val_bf, Mf, DD, DD);

  // off|logits = qn @ Wcat + bias_cat (fp32)
  gemm_bf16<64, 128, 2, 2, 0, 0, 0><<<dim3(1, Mq / 64), 256, 0, stream>>>(
      qn_bf, Wcat_t, bias_cat, nullptr, off, Mq, 128, DD);

  // fused softmax + bilinear sampling -> s (bf16)
  sample_kernel<<<Mq, 192, 0, stream>>>(val_bf, off, refp, s_bf);

  // q2 = query + s @ Wo + bo -> bf16, XCD-swizzled (189 m-tiles, 6 n-tiles)
  gemm_bf16<128, 128, 2, 2, 1, 1, 6><<<((Mq / 128 + 7) / 8) * 8 * 6, 256, 0, stream>>>(
      s_bf, Wo_t, bo, query, q2_bf, Mq, DD, DD);

  // ln2 = LN(q2_bf) -> qn_bf (reuse)
  ln_kernel<u16><<<Mq, 256, 0, stream>>>(q2_bf, ffn_g, ffn_b, qn_bf);

  // h = ln2 @ W1 + b1 (bf16)
  gemm_bf16<64, 192, 1, 4, 0, 1, 0><<<dim3(1, Mq / 64), 256, 0, stream>>>(
      qn_bf, W1_t, b1, nullptr, h_bf, Mq, HID, DD);

  // depthwise conv + GELU
  {
    size_t total = (size_t)BB * NN * HID;
    int blocks = (int)((total + 255) / 256);
    dwconv_gelu_kernel<<<blocks, 256, 0, stream>>>(h_bf, dw_w, dw_b, h2_bf);
  }

  // out = q2 + h2 @ W2 + b2 (fp32 final), XCD-swizzled
  gemm_bf16<128, 128, 2, 2, 2, 0, 6><<<((Mq / 128 + 7) / 8) * 8 * 6, 256, 0, stream>>>(
      h2_bf, W2_t, b2, q2_bf, out, Mq, DD, HID);
}